// Round 5
// baseline (516.247 us; speedup 1.0000x reference)
//
#include <hip/hip_runtime.h>
#include <cstdint>
#include <cstddef>

#define E_DIM   1024
#define NHEADS  16
#define DHEAD   64
#define BATCH   8
#define SEQ     1024
#define MROWS   (BATCH*SEQ)   // 8192

#define LOG2E 1.44269504f

typedef __bf16 bf16;
typedef __attribute__((ext_vector_type(8))) __bf16 bf16x8;
typedef __attribute__((ext_vector_type(4))) __bf16 bf16x4;
typedef __attribute__((ext_vector_type(4))) float f32x4;

typedef const __attribute__((address_space(1))) unsigned int gu32;
typedef __attribute__((address_space(3))) unsigned int lu32;

// ---------------------------------------------------------------------------
// split fp32 -> bf16 hi + bf16 lo
// ---------------------------------------------------------------------------
__global__ __launch_bounds__(256)
void split_kernel(const float* __restrict__ src, bf16* __restrict__ hi,
                  bf16* __restrict__ lo, int n4)
{
    int i = blockIdx.x * 256 + threadIdx.x;
    if (i >= n4) return;
    float4 x = ((const float4*)src)[i];
    bf16x4 h, l;
    h[0] = (bf16)x.x; l[0] = (bf16)(x.x - (float)h[0]);
    h[1] = (bf16)x.y; l[1] = (bf16)(x.y - (float)h[1]);
    h[2] = (bf16)x.z; l[2] = (bf16)(x.z - (float)h[2]);
    h[3] = (bf16)x.w; l[3] = (bf16)(x.w - (float)h[3]);
    ((bf16x4*)hi)[i] = h;
    ((bf16x4*)lo)[i] = l;
}

// fp32 -> bf16 with scale (mask pre-scaled by log2e for exp2-domain softmax)
__global__ __launch_bounds__(256)
void cvt_bf16_kernel(const float* __restrict__ src, bf16* __restrict__ dst,
                     float scale, int n4)
{
    int i = blockIdx.x * 256 + threadIdx.x;
    if (i >= n4) return;
    float4 x = ((const float4*)src)[i];
    bf16x4 h;
    h[0] = (bf16)(x.x * scale); h[1] = (bf16)(x.y * scale);
    h[2] = (bf16)(x.z * scale); h[3] = (bf16)(x.w * scale);
    ((bf16x4*)dst)[i] = h;
}

// ---------------------------------------------------------------------------
// MFMA GEMM, split-bf16, fused 3-term K-loop:
//   acc += Ahi.Whi + Ahi.Wlo + Alo.Whi
// THIS ROUND: the kernel is TILE-TRAFFIC-BOUND (524 MB/GEMM at 128^2 tiles
// == measured 87us at ~6 TB/s; MFMA floor is only 25us). Restructure:
//   - BM=256 x BN=128 tiles -> 396 MB traffic, grid exactly 256 (1 block/CU)
//   - XCD swizzle: mTile = (id&7)+8*((id>>3)&3), nTile = id>>5 so all 8
//     N-blocks sharing an A-panel land on ONE XCD -> A re-reads hit L2.
//   - 512 thr / 8 waves (4M x 2N), wave tile 64x64, acc[4][4], LDS 96 KB
//     double-buffered, 6 global_load_lds per k-step, counted vmcnt(6).
// mode 0: outF[m*N+n] fp32 | mode 1: bf16 scatter (B,H,T,Dh) | mode 2: (B,H,Dh,T)
// ---------------------------------------------------------------------------
__global__ __launch_bounds__(512, 2)
void gemm_nt_mfma(const bf16* __restrict__ Ahi, const bf16* __restrict__ Alo,
                  const bf16* __restrict__ Whi, const bf16* __restrict__ Wlo,
                  const float* __restrict__ bias,
                  float* __restrict__ outF, bf16* __restrict__ outHi,
                  int M, int N, int K, int mode)
{
    __shared__ bf16 Ahs[2][256 * 32];   // 32 KB
    __shared__ bf16 Als[2][256 * 32];   // 32 KB
    __shared__ bf16 Whs[2][128 * 32];   // 16 KB
    __shared__ bf16 Wls[2][128 * 32];   // 16 KB

    const int tid  = threadIdx.x;       // 0..511
    const int lane = tid & 63;
    const int wid  = tid >> 6;          // 0..7
    const int wm = (wid >> 1) * 64;     // 4 row-groups of 64
    const int wn = (wid & 1) * 64;      // 2 col-groups of 64
    const int fr = lane & 15;
    const int fq = lane >> 4;                       // logical k-slot
    const int fk = ((fq + (fr >> 1)) & 3) * 8;      // physical slot (constant/lane)

    // XCD-colocating swizzle: linear id = bx + 8*by; XCD ~ id%8.
    // mTile%8 == id%8 -> the 8 nTiles sharing an A-panel share an XCD.
    const int id = blockIdx.x + 8 * blockIdx.y;
    const int mTile = (id & 7) + 8 * ((id >> 3) & 3);   // 0..31
    const int nTile = id >> 5;                          // 0..7
    const int mBase = mTile * 256;
    const int nBase = nTile * 128;

    const int rowA0 = tid >> 2;         // 0..127 (LDS dest row of this lane)
    // logical k-slot this lane stages so linear LDS dest holds rotated layout
    const int colA0 = (((tid & 3) - ((tid >> 3) & 3)) & 3) * 8;

    const int dcol = lane & 15;
    float bv[4];
#pragma unroll
    for (int bn = 0; bn < 4; ++bn)
        bv[bn] = bias[nBase + wn + bn * 16 + dcol];

    f32x4 acc[4][4];
#pragma unroll
    for (int i = 0; i < 4; ++i)
#pragma unroll
        for (int j = 0; j < 4; ++j) acc[i][j] = (f32x4){0.f, 0.f, 0.f, 0.f};

    // loop-carried staging pointers (advance by 32 bf16 per k-step)
    const bf16* pAh0 = Ahi + (size_t)(mBase + rowA0) * K + colA0;
    const bf16* pAh1 = pAh0 + (size_t)128 * K;
    const bf16* pAl0 = Alo + (size_t)(mBase + rowA0) * K + colA0;
    const bf16* pAl1 = pAl0 + (size_t)128 * K;
    const bf16* pWh  = Whi + (size_t)(nBase + rowA0) * K + colA0;
    const bf16* pWl  = Wlo + (size_t)(nBase + rowA0) * K + colA0;

    auto stage = [&](int bi) {
        __builtin_amdgcn_global_load_lds((gu32*)pAh0, (lu32*)&Ahs[bi][wid * 512],        16, 0, 0);
        __builtin_amdgcn_global_load_lds((gu32*)pAh1, (lu32*)&Ahs[bi][4096 + wid * 512], 16, 0, 0);
        __builtin_amdgcn_global_load_lds((gu32*)pAl0, (lu32*)&Als[bi][wid * 512],        16, 0, 0);
        __builtin_amdgcn_global_load_lds((gu32*)pAl1, (lu32*)&Als[bi][4096 + wid * 512], 16, 0, 0);
        __builtin_amdgcn_global_load_lds((gu32*)pWh,  (lu32*)&Whs[bi][wid * 512],        16, 0, 0);
        __builtin_amdgcn_global_load_lds((gu32*)pWl,  (lu32*)&Wls[bi][wid * 512],        16, 0, 0);
        pAh0 += 32; pAh1 += 32; pAl0 += 32; pAl1 += 32; pWh += 32; pWl += 32;
    };

    stage(0);

    const int NIT = K >> 5;
#pragma unroll 1
    for (int it = 0; it < NIT; ++it) {
        const int cur = it & 1;
        if (it + 1 < NIT) {
            stage(cur ^ 1);
            // wait until only the 6 just-issued prefetch loads remain ->
            // current buffer's 6 loads have landed in LDS.
            asm volatile("s_waitcnt vmcnt(6)" ::: "memory");
        } else {
            asm volatile("s_waitcnt vmcnt(0)" ::: "memory");
        }
        __builtin_amdgcn_s_barrier();   // all waves' stage-loads for cur landed

        const bf16* As = Ahs[cur];
        const bf16* Al = Als[cur];
        const bf16* Ws = Whs[cur];
        const bf16* Wl = Wls[cur];

        bf16x8 afh[4], afl[4], bfh[4], bfl[4];
#pragma unroll
        for (int am = 0; am < 4; ++am) {
            afh[am] = *(const bf16x8*)&As[(wm + am * 16 + fr) * 32 + fk];
            afl[am] = *(const bf16x8*)&Al[(wm + am * 16 + fr) * 32 + fk];
        }
#pragma unroll
        for (int bn = 0; bn < 4; ++bn) {
            bfh[bn] = *(const bf16x8*)&Ws[(wn + bn * 16 + fr) * 32 + fk];
            bfl[bn] = *(const bf16x8*)&Wl[(wn + bn * 16 + fr) * 32 + fk];
        }
        __builtin_amdgcn_s_setprio(1);
#pragma unroll
        for (int am = 0; am < 4; ++am)
#pragma unroll
            for (int bn = 0; bn < 4; ++bn) {
                acc[am][bn] = __builtin_amdgcn_mfma_f32_16x16x32_bf16(afh[am], bfh[bn], acc[am][bn], 0, 0, 0);
                acc[am][bn] = __builtin_amdgcn_mfma_f32_16x16x32_bf16(afh[am], bfl[bn], acc[am][bn], 0, 0, 0);
                acc[am][bn] = __builtin_amdgcn_mfma_f32_16x16x32_bf16(afl[am], bfh[bn], acc[am][bn], 0, 0, 0);
            }
        __builtin_amdgcn_s_setprio(0);
        __builtin_amdgcn_s_barrier();   // safe for next iter's stage to overwrite cur
    }

    const int drow = (lane >> 4) * 4;
#pragma unroll
    for (int bn = 0; bn < 4; ++bn) {
        const int col = nBase + wn + bn * 16 + dcol;
#pragma unroll
        for (int am = 0; am < 4; ++am) {
#pragma unroll
            for (int r = 0; r < 4; ++r) {
                const int row = mBase + wm + am * 16 + drow + r;
                const float v = acc[am][bn][r] + bv[bn];
                if (mode == 0) {
                    outF[(size_t)row * N + col] = v;
                } else {
                    const int b = row >> 10, t = row & 1023;
                    const int h = col >> 6,  d = col & 63;
                    size_t idx;
                    if (mode == 1)
                        idx = (((size_t)(b * NHEADS + h)) * SEQ + t) * DHEAD + d;
                    else
                        idx = (((size_t)(b * NHEADS + h)) * DHEAD + d) * SEQ + t;
                    outHi[idx] = (bf16)v;
                }
            }
        }
    }
}

// ---------------------------------------------------------------------------
// MFMA flash attention, S^T formulation, q-tile 64, double-buffered staging.
// (unchanged this round — isolating the GEMM traffic experiment)
// ---------------------------------------------------------------------------
__global__ __launch_bounds__(256)
void attn_mfma_kernel(const bf16* __restrict__ qkv,
                      const bf16* __restrict__ mask_bf,     // pre-scaled by log2e
                      const unsigned char* __restrict__ kpad,
                      bf16* __restrict__ ctx_hi, bf16* __restrict__ ctx_lo)
{
    __shared__ bf16 Ks [2][4096];               // 16 KB
    __shared__ bf16 Vts[2][4096];               // 16 KB
    __shared__ bf16 Pn[4][1024];                // 8 KB, XOR-swizzled, wave-private

    const int tid  = threadIdx.x;
    const int lane = tid & 63;
    const int wid  = tid >> 6;
    const int c16  = lane & 15;
    const int quad = lane >> 4;

    const int bh = blockIdx.x;             // 0..127
    const int qt = blockIdx.y;             // 0..15
    const int b = bh >> 4, h = bh & 15;

    const size_t seg = (size_t)MROWS * E_DIM;
    const size_t headoff = (size_t)bh * SEQ * DHEAD;
    const bf16* Q_g  = qkv + headoff;
    const bf16* K_g  = qkv + seg + headoff;
    const bf16* Vt_g = qkv + 2 * seg + headoff;   // [d][t]

    const int qglob = qt * 64 + wid * 16 + c16;

    bf16x8 qf[2];
#pragma unroll
    for (int ks = 0; ks < 2; ++ks)
        qf[ks] = *(const bf16x8*)&Q_g[(size_t)qglob * DHEAD + quad * 8 + ks * 32];

    float l_i = 0.f;
    f32x4 oacc[4];
#pragma unroll
    for (int dt = 0; dt < 4; ++dt) oacc[dt] = (f32x4){0.f, 0.f, 0.f, 0.f};

    const int row0 = tid >> 3,         c0 = (tid & 7) ^ (row0 & 7);
    const int row1 = (tid + 256) >> 3, c1 = ((tid + 256) & 7) ^ (row1 & 7);

    auto stage = [&](int kt, int bi) {
        const int ktb = kt * 64;
        const size_t k0 = (size_t)(ktb + row0) * DHEAD + c0 * 8;
        const size_t k1 = (size_t)(ktb + row1) * DHEAD + c1 * 8;
        const size_t v0 = (size_t)row0 * SEQ + ktb + c0 * 8;
        const size_t v1 = (size_t)row1 * SEQ + ktb + c1 * 8;
        __builtin_amdgcn_global_load_lds((gu32*)(K_g + k0),  (lu32*)&Ks [bi][wid * 512],        16, 0, 0);
        __builtin_amdgcn_global_load_lds((gu32*)(K_g + k1),  (lu32*)&Ks [bi][2048 + wid * 512], 16, 0, 0);
        __builtin_amdgcn_global_load_lds((gu32*)(Vt_g + v0), (lu32*)&Vts[bi][wid * 512],        16, 0, 0);
        __builtin_amdgcn_global_load_lds((gu32*)(Vt_g + v1), (lu32*)&Vts[bi][2048 + wid * 512], 16, 0, 0);
    };

    stage(0, 0);
    __syncthreads();

    const int pxor = (c16 & 7) << 3;
    const size_t kpb = (size_t)b * SEQ + quad * 4;

#pragma unroll 1
    for (int kt = 0; kt < 16; ++kt) {
        const int cur = kt & 1;
        const int ktb = kt * 64;

        // mask (bf16, pre-scaled) + kpad loads FIRST
        bf16x4 mvh[4];
        unsigned kpu[4];
#pragma unroll
        for (int st = 0; st < 4; ++st) {
            mvh[st] = *(const bf16x4*)&mask_bf[(size_t)qglob * SEQ + ktb + st * 16 + quad * 4];
            kpu[st] = *(const unsigned*)&kpad[kpb + ktb + st * 16];
        }

        if (kt < 15) stage(kt + 1, cur ^ 1);

        // ---- S^T = K.Q^T ----
        f32x4 sacc[4];
#pragma unroll
        for (int st = 0; st < 4; ++st) sacc[st] = (f32x4){0.f, 0.f, 0.f, 0.f};
        __builtin_amdgcn_s_setprio(1);
#pragma unroll
        for (int st = 0; st < 4; ++st) {
            const int row = st * 16 + c16;
            const int sw  = row & 7;
#pragma unroll
            for (int ks = 0; ks < 2; ++ks) {
                const int cp = ((quad + ks * 4) ^ sw);
                bf16x8 kh = *(const bf16x8*)&Ks[cur][(row * 8 + cp) * 8];
                sacc[st] = __builtin_amdgcn_mfma_f32_16x16x32_bf16(kh, qf[ks], sacc[st], 0, 0, 0);
            }
        }
        __builtin_amdgcn_s_setprio(0);

        // ---- softmax numerator (fixed exp2 base; no max tracking) ----
        float s[16];
#pragma unroll
        for (int st = 0; st < 4; ++st) {
#pragma unroll
            for (int r = 0; r < 4; ++r)
                s[st * 4 + r] = fmaf(sacc[st][r], 0.125f * LOG2E, (float)mvh[st][r]);
        }
        // kpad: wave-uniform guard — all-valid tiles skip the select chain
        if (__any((kpu[0] | kpu[1] | kpu[2] | kpu[3]) != 0u)) {
#pragma unroll
            for (int st = 0; st < 4; ++st)
#pragma unroll
                for (int r = 0; r < 4; ++r)
                    if ((kpu[st] >> (r * 8)) & 0xff) s[st * 4 + r] = -2e30f;
        }
        float p[16];
#pragma unroll
        for (int i = 0; i < 16; ++i)
            p[i] = __builtin_amdgcn_exp2f(fminf(s[i], 30.f));   // clip = overflow guard
        // tree sum (depth 4)
        float u8[8];
#pragma unroll
        for (int i = 0; i < 8; ++i) u8[i] = p[i] + p[i + 8];
#pragma unroll
        for (int i = 0; i < 4; ++i) u8[i] += u8[i + 4];
        float ps = (u8[0] + u8[1]) + (u8[2] + u8[3]);
        ps += __shfl_xor(ps, 16, 64);
        ps += __shfl_xor(ps, 32, 64);
        l_i += ps;

        // ---- P (bf16) via XOR-swizzled wave-private LDS ----
#pragma unroll
        for (int st = 0; st < 4; ++st) {
            bf16x4 ph;
#pragma unroll
            for (int r = 0; r < 4; ++r) ph[r] = (bf16)p[st * 4 + r];
            *(bf16x4*)&Pn[wid][c16 * 64 + ((st * 16 + quad * 4) ^ pxor)] = ph;
        }
        bf16x8 pf[2];
#pragma unroll
        for (int ks = 0; ks < 2; ++ks)
            pf[ks] = *(const bf16x8*)&Pn[wid][c16 * 64 + ((ks * 32 + quad * 8) ^ pxor)];

        // ---- O^T += V^T.P ----
        __builtin_amdgcn_s_setprio(1);
#pragma unroll
        for (int dt = 0; dt < 4; ++dt) {
            const int row = dt * 16 + c16;
            const int sw  = row & 7;
#pragma unroll
            for (int ks = 0; ks < 2; ++ks) {
                const int cp = ((quad + ks * 4) ^ sw);
                bf16x8 vh = *(const bf16x8*)&Vts[cur][(row * 8 + cp) * 8];
                oacc[dt] = __builtin_amdgcn_mfma_f32_16x16x32_bf16(vh, pf[ks], oacc[dt], 0, 0, 0);
            }
        }
        __builtin_amdgcn_s_setprio(0);

        __syncthreads();   // drains prefetch(kt+1); guards buffer reuse
    }

    // ---- epilogue: split O into hi/lo for the out-projection ----
    const float invl = 1.0f / l_i;
#pragma unroll
    for (int dt = 0; dt < 4; ++dt) {
        bf16x4 oh, ol;
#pragma unroll
        for (int r = 0; r < 4; ++r) {
            float v = oacc[dt][r] * invl;
            oh[r] = (bf16)v;
            ol[r] = (bf16)(v - (float)oh[r]);
        }
        size_t idx = ((size_t)b * SEQ + qglob) * E_DIM + h * DHEAD + dt * 16 + quad * 4;
        *(bf16x4*)&ctx_hi[idx] = oh;
        *(bf16x4*)&ctx_lo[idx] = ol;
    }
}

// ---------------------------------------------------------------------------
extern "C" void kernel_launch(void* const* d_in, const int* in_sizes, int n_in,
                              void* d_out, int out_size, void* d_ws, size_t ws_size,
                              hipStream_t stream)
{
    const float* inputs[3] = { (const float*)d_in[0], (const float*)d_in[1],
                               (const float*)d_in[2] };
    const unsigned char* kpad = (const unsigned char*)d_in[3];
    const float* attn_mask = (const float*)d_in[4];
    const float* w_in  = (const float*)d_in[5];
    const float* b_in  = (const float*)d_in[6];
    const float* w_out = (const float*)d_in[7];
    const float* b_out = (const float*)d_in[8];
    float* out = (float*)d_out;

    char* ws = (char*)d_ws;
    const size_t MB = 1024 * 1024;
    bf16* bufA_hi  = (bf16*)(ws + 0 * MB);
    bf16* bufA_lo  = (bf16*)(ws + 16 * MB);
    bf16* w_in_hi  = (bf16*)(ws + 32 * MB);
    bf16* w_in_lo  = (bf16*)(ws + 38 * MB);
    bf16* w_out_hi = (bf16*)(ws + 44 * MB);
    bf16* w_out_lo = (bf16*)(ws + 46 * MB);
    bf16* qkv      = (bf16*)(ws + 48 * MB);
    bf16* mask_bf  = (bf16*)(ws + 96 * MB);   // 2MB bf16, pre-scaled by log2e
    bf16* ctx_hi   = (bf16*)(ws + 0 * MB);
    bf16* ctx_lo   = (bf16*)(ws + 16 * MB);

    const size_t seg = (size_t)MROWS * E_DIM;

    split_kernel<<<(3 * E_DIM * E_DIM / 4 + 255) / 256, 256, 0, stream>>>(
        w_in, w_in_hi, w_in_lo, 3 * E_DIM * E_DIM / 4);
    split_kernel<<<(E_DIM * E_DIM / 4 + 255) / 256, 256, 0, stream>>>(
        w_out, w_out_hi, w_out_lo, E_DIM * E_DIM / 4);
    cvt_bf16_kernel<<<(SEQ * SEQ / 4 + 255) / 256, 256, 0, stream>>>(
        attn_mask, mask_bf, LOG2E, SEQ * SEQ / 4);

    for (int z = 0; z < 3; ++z) {
        split_kernel<<<(int)(seg / 4 / 256), 256, 0, stream>>>(
            inputs[z], bufA_hi, bufA_lo, (int)(seg / 4));
        gemm_nt_mfma<<<dim3(8, 32), 512, 0, stream>>>(
            bufA_hi, bufA_lo,
            w_in_hi + (size_t)z * E_DIM * E_DIM, w_in_lo + (size_t)z * E_DIM * E_DIM,
            b_in + z * E_DIM,
            nullptr, qkv + (size_t)z * seg,
            MROWS, E_DIM, E_DIM, (z == 2) ? 2 : 1);
    }

    attn_mfma_kernel<<<dim3(BATCH * NHEADS, SEQ / 64), 256, 0, stream>>>(
        qkv, mask_bf, kpad, ctx_hi, ctx_lo);

    gemm_nt_mfma<<<dim3(8, 32), 512, 0, stream>>>(
        ctx_hi, ctx_lo, w_out_hi, w_out_lo, b_out,
        out, nullptr, MROWS, E_DIM, E_DIM, 0);
}

// Round 6
// 465.997 us; speedup vs baseline: 1.1078x; 1.1078x over previous
//
#include <hip/hip_runtime.h>
#include <cstdint>
#include <cstddef>

#define E_DIM   1024
#define NHEADS  16
#define DHEAD   64
#define BATCH   8
#define SEQ     1024
#define MROWS   (BATCH*SEQ)   // 8192

#define LOG2E 1.44269504f

typedef __bf16 bf16;
typedef __attribute__((ext_vector_type(8))) __bf16 bf16x8;
typedef __attribute__((ext_vector_type(4))) __bf16 bf16x4;
typedef __attribute__((ext_vector_type(4))) float f32x4;

typedef const __attribute__((address_space(1))) unsigned int gu32;
typedef __attribute__((address_space(3))) unsigned int lu32;

// ---------------------------------------------------------------------------
// split fp32 -> bf16 hi + bf16 lo  (weights only now)
// ---------------------------------------------------------------------------
__global__ __launch_bounds__(256)
void split_kernel(const float* __restrict__ src, bf16* __restrict__ hi,
                  bf16* __restrict__ lo, int n4)
{
    int i = blockIdx.x * 256 + threadIdx.x;
    if (i >= n4) return;
    float4 x = ((const float4*)src)[i];
    bf16x4 h, l;
    h[0] = (bf16)x.x; l[0] = (bf16)(x.x - (float)h[0]);
    h[1] = (bf16)x.y; l[1] = (bf16)(x.y - (float)h[1]);
    h[2] = (bf16)x.z; l[2] = (bf16)(x.z - (float)h[2]);
    h[3] = (bf16)x.w; l[3] = (bf16)(x.w - (float)h[3]);
    ((bf16x4*)hi)[i] = h;
    ((bf16x4*)lo)[i] = l;
}

// fp32 -> bf16 with scale (mask pre-scaled by log2e for exp2-domain softmax)
__global__ __launch_bounds__(256)
void cvt_bf16_kernel(const float* __restrict__ src, bf16* __restrict__ dst,
                     float scale, int n4)
{
    int i = blockIdx.x * 256 + threadIdx.x;
    if (i >= n4) return;
    float4 x = ((const float4*)src)[i];
    bf16x4 h;
    h[0] = (bf16)(x.x * scale); h[1] = (bf16)(x.y * scale);
    h[2] = (bf16)(x.z * scale); h[3] = (bf16)(x.w * scale);
    ((bf16x4*)dst)[i] = h;
}

// ---------------------------------------------------------------------------
// MFMA GEMM, split-bf16 3-term K-loop: acc += Ahi.Whi + Ahi.Wlo + Alo.Whi
// r4 config (best measured): BM=BN=128, 512 thr / 8 waves, wave tile 32x64,
// double-buffered LDS 64KB, distance-1 prefetch, counted vmcnt(4).
// THIS ROUND: AMODE=1 fuses the input split INTO the gemm — A is staged as
// raw fp32 (same bytes as hi+lo bf16) and hi/lo fragments are derived
// in-register (cvt/sub/cvt, ~48 VALU/wave/iter, co-issues with MFMA).
// Removes the 3 split dispatches and their 64MB round-trips.
// AMODE=0: A is pre-split bf16 hi/lo (out-projection, ctx from attn).
// mode 0: outF fp32 | mode 1: bf16 scatter (B,H,T,Dh) | mode 2: (B,H,Dh,T)
// ---------------------------------------------------------------------------
template<int AMODE>
__global__ __launch_bounds__(512, 2)
void gemm_nt_mfma(const float* __restrict__ Af,
                  const bf16* __restrict__ Ahi, const bf16* __restrict__ Alo,
                  const bf16* __restrict__ Whi, const bf16* __restrict__ Wlo,
                  const float* __restrict__ bias,
                  float* __restrict__ outF, bf16* __restrict__ outHi,
                  int M, int N, int K, int mode)
{
    // A buffer: 16KB/stage = either 128x32 fp32, or 2 x (128x32 bf16) hi+lo
    __shared__ char  smemA[2][16384];
    __shared__ bf16  Whs[2][128 * 32];
    __shared__ bf16  Wls[2][128 * 32];

    const int tid  = threadIdx.x;       // 0..511
    const int lane = tid & 63;
    const int wid  = tid >> 6;          // 0..7
    const int wm = (wid >> 1) * 32;
    const int wn = (wid & 1) * 64;
    const int fr = lane & 15;
    const int fq = lane >> 4;                       // logical k-slot (8 elems)
    const int fk = ((fq + (fr >> 1)) & 3) * 8;      // W phys slot (per-lane const)

    const int mBase = blockIdx.y * 128;
    const int nBase = blockIdx.x * 128;

    // --- staging geometry ---
    // W (bf16): 4 lanes/row, 16B each
    const int rowW  = tid >> 2;                                 // 0..127
    const int colW  = (((tid & 3) - ((tid >> 3) & 3)) & 3) * 8; // rotated slot
    // A fp32 (AMODE=1): 8 lanes/row, 16B each, phys slot rotated by row&7
    const int rowAf  = tid >> 3;                                // 0..63 (+64 2nd)
    const int slotAf = ((tid & 7) - (rowAf & 7)) & 7;           // logical slot

    const int dcol = lane & 15;
    float bv[4];
#pragma unroll
    for (int bn = 0; bn < 4; ++bn)
        bv[bn] = bias[nBase + wn + bn * 16 + dcol];

    f32x4 acc[2][4];
#pragma unroll
    for (int i = 0; i < 2; ++i)
#pragma unroll
        for (int j = 0; j < 4; ++j) acc[i][j] = (f32x4){0.f, 0.f, 0.f, 0.f};

    // loop-carried staging pointers (advance 32 elems per k-step)
    const float* pAf0 = Af  + (size_t)(mBase + rowAf) * K + slotAf * 4;
    const float* pAf1 = pAf0 + (size_t)64 * K;
    const bf16*  pAh  = Ahi + (size_t)(mBase + rowW) * K + colW;
    const bf16*  pAl  = Alo + (size_t)(mBase + rowW) * K + colW;
    const bf16*  pWh  = Whi + (size_t)(nBase + rowW) * K + colW;
    const bf16*  pWl  = Wlo + (size_t)(nBase + rowW) * K + colW;

    auto stage = [&](int bi) {
        if (AMODE == 1) {
            float* As = (float*)smemA[bi];
            __builtin_amdgcn_global_load_lds((gu32*)pAf0, (lu32*)&As[wid * 256],        16, 0, 0);
            __builtin_amdgcn_global_load_lds((gu32*)pAf1, (lu32*)&As[2048 + wid * 256], 16, 0, 0);
            pAf0 += 32; pAf1 += 32;
        } else {
            bf16* Ah = (bf16*)smemA[bi];
            bf16* Al = Ah + 4096;
            __builtin_amdgcn_global_load_lds((gu32*)pAh, (lu32*)&Ah[wid * 512], 16, 0, 0);
            __builtin_amdgcn_global_load_lds((gu32*)pAl, (lu32*)&Al[wid * 512], 16, 0, 0);
            pAh += 32; pAl += 32;
        }
        __builtin_amdgcn_global_load_lds((gu32*)pWh, (lu32*)&Whs[bi][wid * 512], 16, 0, 0);
        __builtin_amdgcn_global_load_lds((gu32*)pWl, (lu32*)&Wls[bi][wid * 512], 16, 0, 0);
        pWh += 32; pWl += 32;
    };

    stage(0);

    const int NIT = K >> 5;
#pragma unroll 1
    for (int it = 0; it < NIT; ++it) {
        const int cur = it & 1;
        if (it + 1 < NIT) {
            stage(cur ^ 1);
            asm volatile("s_waitcnt vmcnt(4)" ::: "memory");
        } else {
            asm volatile("s_waitcnt vmcnt(0)" ::: "memory");
        }
        __builtin_amdgcn_s_barrier();   // cur buffer's loads landed for all waves

        bf16x8 afh[2], afl[2], bfh[4], bfl[4];
        if (AMODE == 1) {
            const float* As = (const float*)smemA[cur];
#pragma unroll
            for (int am = 0; am < 2; ++am) {
                const int row = wm + am * 16 + fr;
                const float* Ar = &As[row * 32];
                f32x4 a0 = *(const f32x4*)&Ar[((2 * fq     + (fr & 7)) & 7) * 4];
                f32x4 a1 = *(const f32x4*)&Ar[((2 * fq + 1 + (fr & 7)) & 7) * 4];
                bf16x8 h, l;
#pragma unroll
                for (int j = 0; j < 4; ++j) {
                    h[j]     = (bf16)a0[j];
                    l[j]     = (bf16)(a0[j] - (float)h[j]);
                    h[j + 4] = (bf16)a1[j];
                    l[j + 4] = (bf16)(a1[j] - (float)h[j + 4]);
                }
                afh[am] = h; afl[am] = l;
            }
        } else {
            const bf16* Ah = (const bf16*)smemA[cur];
            const bf16* Al = Ah + 4096;
#pragma unroll
            for (int am = 0; am < 2; ++am) {
                afh[am] = *(const bf16x8*)&Ah[(wm + am * 16 + fr) * 32 + fk];
                afl[am] = *(const bf16x8*)&Al[(wm + am * 16 + fr) * 32 + fk];
            }
        }
#pragma unroll
        for (int bn = 0; bn < 4; ++bn) {
            bfh[bn] = *(const bf16x8*)&Whs[cur][(wn + bn * 16 + fr) * 32 + fk];
            bfl[bn] = *(const bf16x8*)&Wls[cur][(wn + bn * 16 + fr) * 32 + fk];
        }
        __builtin_amdgcn_s_setprio(1);
#pragma unroll
        for (int am = 0; am < 2; ++am)
#pragma unroll
            for (int bn = 0; bn < 4; ++bn) {
                acc[am][bn] = __builtin_amdgcn_mfma_f32_16x16x32_bf16(afh[am], bfh[bn], acc[am][bn], 0, 0, 0);
                acc[am][bn] = __builtin_amdgcn_mfma_f32_16x16x32_bf16(afh[am], bfl[bn], acc[am][bn], 0, 0, 0);
                acc[am][bn] = __builtin_amdgcn_mfma_f32_16x16x32_bf16(afl[am], bfh[bn], acc[am][bn], 0, 0, 0);
            }
        __builtin_amdgcn_s_setprio(0);
        __builtin_amdgcn_s_barrier();   // safe for next iter's stage to overwrite cur
    }

    const int drow = (lane >> 4) * 4;
#pragma unroll
    for (int bn = 0; bn < 4; ++bn) {
        const int col = nBase + wn + bn * 16 + dcol;
#pragma unroll
        for (int am = 0; am < 2; ++am) {
#pragma unroll
            for (int r = 0; r < 4; ++r) {
                const int row = mBase + wm + am * 16 + drow + r;
                const float v = acc[am][bn][r] + bv[bn];
                if (mode == 0) {
                    outF[(size_t)row * N + col] = v;
                } else {
                    const int b = row >> 10, t = row & 1023;
                    const int h = col >> 6,  d = col & 63;
                    size_t idx;
                    if (mode == 1)
                        idx = (((size_t)(b * NHEADS + h)) * SEQ + t) * DHEAD + d;
                    else
                        idx = (((size_t)(b * NHEADS + h)) * DHEAD + d) * SEQ + t;
                    outHi[idx] = (bf16)v;
                }
            }
        }
    }
}

// ---------------------------------------------------------------------------
// MFMA flash attention, S^T formulation, double-buffered staging.
// THIS ROUND: QBLK=128 (512 threads / 8 waves per block). Per-wave work is
// identical; K/V staging amortizes over 2x q-rows (2 loads/iter not 4),
// LDS 48KB -> 3 blocks x 8 waves = 24 waves/CU (75% occupancy, was 39%).
// Grid (bh=128, qt=8): id%8 = bh%8 keeps all q-tiles of a head on one XCD.
// ---------------------------------------------------------------------------
__global__ __launch_bounds__(512)
void attn_mfma_kernel(const bf16* __restrict__ qkv,
                      const bf16* __restrict__ mask_bf,     // pre-scaled by log2e
                      const unsigned char* __restrict__ kpad,
                      bf16* __restrict__ ctx_hi, bf16* __restrict__ ctx_lo)
{
    __shared__ bf16 Ks [2][4096];               // 16 KB
    __shared__ bf16 Vts[2][4096];               // 16 KB
    __shared__ bf16 Pn[8][1024];                // 16 KB, XOR-swizzled, wave-private

    const int tid  = threadIdx.x;
    const int lane = tid & 63;
    const int wid  = tid >> 6;          // 0..7
    const int c16  = lane & 15;
    const int quad = lane >> 4;

    const int bh = blockIdx.x;             // 0..127
    const int qt = blockIdx.y;             // 0..7
    const int b = bh >> 4, h = bh & 15;

    const size_t seg = (size_t)MROWS * E_DIM;
    const size_t headoff = (size_t)bh * SEQ * DHEAD;
    const bf16* Q_g  = qkv + headoff;
    const bf16* K_g  = qkv + seg + headoff;
    const bf16* Vt_g = qkv + 2 * seg + headoff;   // [d][t]

    const int qglob = qt * 128 + wid * 16 + c16;

    bf16x8 qf[2];
#pragma unroll
    for (int ks = 0; ks < 2; ++ks)
        qf[ks] = *(const bf16x8*)&Q_g[(size_t)qglob * DHEAD + quad * 8 + ks * 32];

    float l_i = 0.f;
    f32x4 oacc[4];
#pragma unroll
    for (int dt = 0; dt < 4; ++dt) oacc[dt] = (f32x4){0.f, 0.f, 0.f, 0.f};

    // 512 threads: 8 lanes/row, 64 rows per staging instr
    const int row0 = tid >> 3;                       // 0..63
    const int c0   = (tid & 7) ^ (row0 & 7);

    auto stage = [&](int kt, int bi) {
        const int ktb = kt * 64;
        const size_t k0 = (size_t)(ktb + row0) * DHEAD + c0 * 8;
        const size_t v0 = (size_t)row0 * SEQ + ktb + c0 * 8;
        __builtin_amdgcn_global_load_lds((gu32*)(K_g + k0),  (lu32*)&Ks [bi][wid * 512], 16, 0, 0);
        __builtin_amdgcn_global_load_lds((gu32*)(Vt_g + v0), (lu32*)&Vts[bi][wid * 512], 16, 0, 0);
    };

    stage(0, 0);
    __syncthreads();

    const int pxor = (c16 & 7) << 3;
    const size_t kpb = (size_t)b * SEQ + quad * 4;

#pragma unroll 1
    for (int kt = 0; kt < 16; ++kt) {
        const int cur = kt & 1;
        const int ktb = kt * 64;

        // mask (bf16, pre-scaled) + kpad loads FIRST
        bf16x4 mvh[4];
        unsigned kpu[4];
#pragma unroll
        for (int st = 0; st < 4; ++st) {
            mvh[st] = *(const bf16x4*)&mask_bf[(size_t)qglob * SEQ + ktb + st * 16 + quad * 4];
            kpu[st] = *(const unsigned*)&kpad[kpb + ktb + st * 16];
        }

        if (kt < 15) stage(kt + 1, cur ^ 1);

        // ---- S^T = K.Q^T ----
        f32x4 sacc[4];
#pragma unroll
        for (int st = 0; st < 4; ++st) sacc[st] = (f32x4){0.f, 0.f, 0.f, 0.f};
        __builtin_amdgcn_s_setprio(1);
#pragma unroll
        for (int st = 0; st < 4; ++st) {
            const int row = st * 16 + c16;
            const int sw  = row & 7;
#pragma unroll
            for (int ks = 0; ks < 2; ++ks) {
                const int cp = ((quad + ks * 4) ^ sw);
                bf16x8 kh = *(const bf16x8*)&Ks[cur][(row * 8 + cp) * 8];
                sacc[st] = __builtin_amdgcn_mfma_f32_16x16x32_bf16(kh, qf[ks], sacc[st], 0, 0, 0);
            }
        }
        __builtin_amdgcn_s_setprio(0);

        // ---- softmax numerator (fixed exp2 base; no max tracking) ----
        float s[16];
#pragma unroll
        for (int st = 0; st < 4; ++st) {
#pragma unroll
            for (int r = 0; r < 4; ++r)
                s[st * 4 + r] = fmaf(sacc[st][r], 0.125f * LOG2E, (float)mvh[st][r]);
        }
        if (__any((kpu[0] | kpu[1] | kpu[2] | kpu[3]) != 0u)) {
#pragma unroll
            for (int st = 0; st < 4; ++st)
#pragma unroll
                for (int r = 0; r < 4; ++r)
                    if ((kpu[st] >> (r * 8)) & 0xff) s[st * 4 + r] = -2e30f;
        }
        float p[16];
#pragma unroll
        for (int i = 0; i < 16; ++i)
            p[i] = __builtin_amdgcn_exp2f(fminf(s[i], 30.f));   // overflow guard
        float u8[8];
#pragma unroll
        for (int i = 0; i < 8; ++i) u8[i] = p[i] + p[i + 8];
#pragma unroll
        for (int i = 0; i < 4; ++i) u8[i] += u8[i + 4];
        float ps = (u8[0] + u8[1]) + (u8[2] + u8[3]);
        ps += __shfl_xor(ps, 16, 64);
        ps += __shfl_xor(ps, 32, 64);
        l_i += ps;

        // ---- P (bf16) via XOR-swizzled wave-private LDS ----
#pragma unroll
        for (int st = 0; st < 4; ++st) {
            bf16x4 ph;
#pragma unroll
            for (int r = 0; r < 4; ++r) ph[r] = (bf16)p[st * 4 + r];
            *(bf16x4*)&Pn[wid][c16 * 64 + ((st * 16 + quad * 4) ^ pxor)] = ph;
        }
        bf16x8 pf[2];
#pragma unroll
        for (int ks = 0; ks < 2; ++ks)
            pf[ks] = *(const bf16x8*)&Pn[wid][c16 * 64 + ((ks * 32 + quad * 8) ^ pxor)];

        // ---- O^T += V^T.P ----
        __builtin_amdgcn_s_setprio(1);
#pragma unroll
        for (int dt = 0; dt < 4; ++dt) {
            const int row = dt * 16 + c16;
            const int sw  = row & 7;
#pragma unroll
            for (int ks = 0; ks < 2; ++ks) {
                const int cp = ((quad + ks * 4) ^ sw);
                bf16x8 vh = *(const bf16x8*)&Vts[cur][(row * 8 + cp) * 8];
                oacc[dt] = __builtin_amdgcn_mfma_f32_16x16x32_bf16(vh, pf[ks], oacc[dt], 0, 0, 0);
            }
        }
        __builtin_amdgcn_s_setprio(0);

        __syncthreads();   // drains prefetch(kt+1); guards buffer reuse
    }

    // ---- epilogue: split O into hi/lo for the out-projection ----
    const float invl = 1.0f / l_i;
#pragma unroll
    for (int dt = 0; dt < 4; ++dt) {
        bf16x4 oh, ol;
#pragma unroll
        for (int r = 0; r < 4; ++r) {
            float v = oacc[dt][r] * invl;
            oh[r] = (bf16)v;
            ol[r] = (bf16)(v - (float)oh[r]);
        }
        size_t idx = ((size_t)b * SEQ + qglob) * E_DIM + h * DHEAD + dt * 16 + quad * 4;
        *(bf16x4*)&ctx_hi[idx] = oh;
        *(bf16x4*)&ctx_lo[idx] = ol;
    }
}

// ---------------------------------------------------------------------------
extern "C" void kernel_launch(void* const* d_in, const int* in_sizes, int n_in,
                              void* d_out, int out_size, void* d_ws, size_t ws_size,
                              hipStream_t stream)
{
    const float* inputs[3] = { (const float*)d_in[0], (const float*)d_in[1],
                               (const float*)d_in[2] };
    const unsigned char* kpad = (const unsigned char*)d_in[3];
    const float* attn_mask = (const float*)d_in[4];
    const float* w_in  = (const float*)d_in[5];
    const float* b_in  = (const float*)d_in[6];
    const float* w_out = (const float*)d_in[7];
    const float* b_out = (const float*)d_in[8];
    float* out = (float*)d_out;

    char* ws = (char*)d_ws;
    const size_t MB = 1024 * 1024;
    bf16* w_in_hi  = (bf16*)(ws + 0 * MB);    // 6MB
    bf16* w_in_lo  = (bf16*)(ws + 6 * MB);    // 6MB
    bf16* w_out_hi = (bf16*)(ws + 12 * MB);   // 2MB
    bf16* w_out_lo = (bf16*)(ws + 14 * MB);   // 2MB
    bf16* qkv      = (bf16*)(ws + 16 * MB);   // 48MB (Q,K,Vt bf16)
    bf16* mask_bf  = (bf16*)(ws + 64 * MB);   // 2MB
    bf16* ctx_hi   = (bf16*)(ws + 66 * MB);   // 16MB
    bf16* ctx_lo   = (bf16*)(ws + 82 * MB);   // 16MB

    const size_t seg = (size_t)MROWS * E_DIM;

    split_kernel<<<(3 * E_DIM * E_DIM / 4 + 255) / 256, 256, 0, stream>>>(
        w_in, w_in_hi, w_in_lo, 3 * E_DIM * E_DIM / 4);
    split_kernel<<<(E_DIM * E_DIM / 4 + 255) / 256, 256, 0, stream>>>(
        w_out, w_out_hi, w_out_lo, E_DIM * E_DIM / 4);
    cvt_bf16_kernel<<<(SEQ * SEQ / 4 + 255) / 256, 256, 0, stream>>>(
        attn_mask, mask_bf, LOG2E, SEQ * SEQ / 4);

    for (int z = 0; z < 3; ++z) {
        gemm_nt_mfma<1><<<dim3(E_DIM / 128, MROWS / 128), 512, 0, stream>>>(
            inputs[z], nullptr, nullptr,
            w_in_hi + (size_t)z * E_DIM * E_DIM, w_in_lo + (size_t)z * E_DIM * E_DIM,
            b_in + z * E_DIM,
            nullptr, qkv + (size_t)z * seg,
            MROWS, E_DIM, E_DIM, (z == 2) ? 2 : 1);
    }

    attn_mfma_kernel<<<dim3(BATCH * NHEADS, SEQ / 128), 512, 0, stream>>>(
        qkv, mask_bf, kpad, ctx_hi, ctx_lo);

    gemm_nt_mfma<0><<<dim3(E_DIM / 128, MROWS / 128), 512, 0, stream>>>(
        nullptr, ctx_hi, ctx_lo, w_out_hi, w_out_lo, b_out,
        out, nullptr, MROWS, E_DIM, E_DIM, 0);
}

// Round 7
// 446.458 us; speedup vs baseline: 1.1563x; 1.0438x over previous
//
#include <hip/hip_runtime.h>
#include <cstdint>
#include <cstddef>

#define E_DIM   1024
#define NHEADS  16
#define DHEAD   64
#define BATCH   8
#define SEQ     1024
#define MROWS   (BATCH*SEQ)   // 8192

#define LOG2E 1.44269504f

typedef __bf16 bf16;
typedef __attribute__((ext_vector_type(8))) __bf16 bf16x8;
typedef __attribute__((ext_vector_type(4))) __bf16 bf16x4;
typedef __attribute__((ext_vector_type(4))) float f32x4;

typedef const __attribute__((address_space(1))) unsigned int gu32;
typedef __attribute__((address_space(3))) unsigned int lu32;

// ---------------------------------------------------------------------------
// split fp32 -> bf16 hi + bf16 lo  (weights only)
// ---------------------------------------------------------------------------
__global__ __launch_bounds__(256)
void split_kernel(const float* __restrict__ src, bf16* __restrict__ hi,
                  bf16* __restrict__ lo, int n4)
{
    int i = blockIdx.x * 256 + threadIdx.x;
    if (i >= n4) return;
    float4 x = ((const float4*)src)[i];
    bf16x4 h, l;
    h[0] = (bf16)x.x; l[0] = (bf16)(x.x - (float)h[0]);
    h[1] = (bf16)x.y; l[1] = (bf16)(x.y - (float)h[1]);
    h[2] = (bf16)x.z; l[2] = (bf16)(x.z - (float)h[2]);
    h[3] = (bf16)x.w; l[3] = (bf16)(x.w - (float)h[3]);
    ((bf16x4*)hi)[i] = h;
    ((bf16x4*)lo)[i] = l;
}

// fp32 -> bf16 with scale (mask pre-scaled by log2e for exp2-domain softmax)
__global__ __launch_bounds__(256)
void cvt_bf16_kernel(const float* __restrict__ src, bf16* __restrict__ dst,
                     float scale, int n4)
{
    int i = blockIdx.x * 256 + threadIdx.x;
    if (i >= n4) return;
    float4 x = ((const float4*)src)[i];
    bf16x4 h;
    h[0] = (bf16)(x.x * scale); h[1] = (bf16)(x.y * scale);
    h[2] = (bf16)(x.z * scale); h[3] = (bf16)(x.w * scale);
    ((bf16x4*)dst)[i] = h;
}

// ---------------------------------------------------------------------------
// MFMA GEMM, split-bf16 3-term K-loop: acc += Ahi.Whi + Ahi.Wlo + Alo.Whi
// BM=BN=128, 512 thr / 8 waves, wave tile 32x64, dbuf LDS 64KB (2 blocks/CU),
// distance-1 prefetch, counted vmcnt(4).
// THIS ROUND (fetch-BW theory): concurrency-aware XCD swizzle
//   mTile=(id&7)+8*(id>>6), nTile=(id>>3)&7
// so each XCD's 64 resident blocks cover 8 mTiles x 8 nTiles -> A-panels and
// W tile L2-resident; A 8x re-reads + W 64x re-reads become L2 hits.
// Also: 3 in-proj GEMMs fused into ONE dispatch (grid 512x3) -> shows up in
// rocprof top-5 with real counters.
// AMODE=1: A staged as raw fp32, hi/lo derived in-register. AMODE=0: bf16 hi/lo.
// out mode (AMODE=1): z<2 -> bf16 scatter (B,H,T,Dh); z=2 -> (B,H,Dh,T).
// ---------------------------------------------------------------------------
template<int AMODE>
__global__ __launch_bounds__(512, 2)
void gemm_nt_mfma(const float* __restrict__ Af0, const float* __restrict__ Af1,
                  const float* __restrict__ Af2,
                  const bf16* __restrict__ Ahi, const bf16* __restrict__ Alo,
                  const bf16* __restrict__ Whi, const bf16* __restrict__ Wlo,
                  const float* __restrict__ bias,
                  float* __restrict__ outF, bf16* __restrict__ outHi,
                  int M, int N, int K)
{
    // A buffer: 16KB/stage = either 128x32 fp32, or 2 x (128x32 bf16) hi+lo
    __shared__ char  smemA[2][16384];
    __shared__ bf16  Whs[2][128 * 32];
    __shared__ bf16  Wls[2][128 * 32];

    const int tid  = threadIdx.x;       // 0..511
    const int lane = tid & 63;
    const int wid  = tid >> 6;          // 0..7
    const int wm = (wid >> 1) * 32;
    const int wn = (wid & 1) * 64;
    const int fr = lane & 15;
    const int fq = lane >> 4;                       // logical k-slot (8 elems)
    const int fk = ((fq + (fr >> 1)) & 3) * 8;      // W phys slot (per-lane const)

    // fused-z selection
    const int z = blockIdx.y;
    const float* Af = (z == 0) ? Af0 : (z == 1) ? Af1 : Af2;
    const bf16* Wh = Whi + (size_t)z * E_DIM * E_DIM;
    const bf16* Wl = Wlo + (size_t)z * E_DIM * E_DIM;
    const float* bs = bias + z * E_DIM;
    const int mode = AMODE ? ((z == 2) ? 2 : 1) : 0;

    // concurrency-aware XCD swizzle (bijective on id<512):
    const int id = blockIdx.x;
    const int mTile = (id & 7) + 8 * (id >> 6);   // 0..63
    const int nTile = (id >> 3) & 7;              // 0..7
    const int mBase = mTile * 128;
    const int nBase = nTile * 128;

    // --- staging geometry ---
    const int rowW  = tid >> 2;                                 // 0..127
    const int colW  = (((tid & 3) - ((tid >> 3) & 3)) & 3) * 8; // rotated slot
    const int rowAf  = tid >> 3;                                // 0..63 (+64 2nd)
    const int slotAf = ((tid & 7) - (rowAf & 7)) & 7;           // logical slot

    const int dcol = lane & 15;
    float bv[4];
#pragma unroll
    for (int bn = 0; bn < 4; ++bn)
        bv[bn] = bs[nBase + wn + bn * 16 + dcol];

    f32x4 acc[2][4];
#pragma unroll
    for (int i = 0; i < 2; ++i)
#pragma unroll
        for (int j = 0; j < 4; ++j) acc[i][j] = (f32x4){0.f, 0.f, 0.f, 0.f};

    // loop-carried staging pointers (advance 32 elems per k-step)
    const float* pAf0 = Af  + (size_t)(mBase + rowAf) * K + slotAf * 4;
    const float* pAf1 = pAf0 + (size_t)64 * K;
    const bf16*  pAh  = Ahi + (size_t)(mBase + rowW) * K + colW;
    const bf16*  pAl  = Alo + (size_t)(mBase + rowW) * K + colW;
    const bf16*  pWh  = Wh + (size_t)(nBase + rowW) * K + colW;
    const bf16*  pWl  = Wl + (size_t)(nBase + rowW) * K + colW;

    auto stage = [&](int bi) {
        if (AMODE == 1) {
            float* As = (float*)smemA[bi];
            __builtin_amdgcn_global_load_lds((gu32*)pAf0, (lu32*)&As[wid * 256],        16, 0, 0);
            __builtin_amdgcn_global_load_lds((gu32*)pAf1, (lu32*)&As[2048 + wid * 256], 16, 0, 0);
            pAf0 += 32; pAf1 += 32;
        } else {
            bf16* Ah = (bf16*)smemA[bi];
            bf16* Al = Ah + 4096;
            __builtin_amdgcn_global_load_lds((gu32*)pAh, (lu32*)&Ah[wid * 512], 16, 0, 0);
            __builtin_amdgcn_global_load_lds((gu32*)pAl, (lu32*)&Al[wid * 512], 16, 0, 0);
        }
        __builtin_amdgcn_global_load_lds((gu32*)pWh, (lu32*)&Whs[bi][wid * 512], 16, 0, 0);
        __builtin_amdgcn_global_load_lds((gu32*)pWl, (lu32*)&Wls[bi][wid * 512], 16, 0, 0);
        pAh += 32; pAl += 32; pWh += 32; pWl += 32;
    };

    stage(0);

    const int NIT = K >> 5;
#pragma unroll 1
    for (int it = 0; it < NIT; ++it) {
        const int cur = it & 1;
        if (it + 1 < NIT) {
            stage(cur ^ 1);
            asm volatile("s_waitcnt vmcnt(4)" ::: "memory");
        } else {
            asm volatile("s_waitcnt vmcnt(0)" ::: "memory");
        }
        __builtin_amdgcn_s_barrier();   // cur buffer's loads landed for all waves

        bf16x8 afh[2], afl[2], bfh[4], bfl[4];
        if (AMODE == 1) {
            const float* As = (const float*)smemA[cur];
#pragma unroll
            for (int am = 0; am < 2; ++am) {
                const int row = wm + am * 16 + fr;
                const float* Ar = &As[row * 32];
                f32x4 a0 = *(const f32x4*)&Ar[((2 * fq     + (fr & 7)) & 7) * 4];
                f32x4 a1 = *(const f32x4*)&Ar[((2 * fq + 1 + (fr & 7)) & 7) * 4];
                bf16x8 h, l;
#pragma unroll
                for (int j = 0; j < 4; ++j) {
                    h[j]     = (bf16)a0[j];
                    l[j]     = (bf16)(a0[j] - (float)h[j]);
                    h[j + 4] = (bf16)a1[j];
                    l[j + 4] = (bf16)(a1[j] - (float)h[j + 4]);
                }
                afh[am] = h; afl[am] = l;
            }
        } else {
            const bf16* Ah = (const bf16*)smemA[cur];
            const bf16* Al = Ah + 4096;
#pragma unroll
            for (int am = 0; am < 2; ++am) {
                afh[am] = *(const bf16x8*)&Ah[(wm + am * 16 + fr) * 32 + fk];
                afl[am] = *(const bf16x8*)&Al[(wm + am * 16 + fr) * 32 + fk];
            }
        }
#pragma unroll
        for (int bn = 0; bn < 4; ++bn) {
            bfh[bn] = *(const bf16x8*)&Whs[cur][(wn + bn * 16 + fr) * 32 + fk];
            bfl[bn] = *(const bf16x8*)&Wls[cur][(wn + bn * 16 + fr) * 32 + fk];
        }
        __builtin_amdgcn_s_setprio(1);
#pragma unroll
        for (int am = 0; am < 2; ++am)
#pragma unroll
            for (int bn = 0; bn < 4; ++bn) {
                acc[am][bn] = __builtin_amdgcn_mfma_f32_16x16x32_bf16(afh[am], bfh[bn], acc[am][bn], 0, 0, 0);
                acc[am][bn] = __builtin_amdgcn_mfma_f32_16x16x32_bf16(afh[am], bfl[bn], acc[am][bn], 0, 0, 0);
                acc[am][bn] = __builtin_amdgcn_mfma_f32_16x16x32_bf16(afl[am], bfh[bn], acc[am][bn], 0, 0, 0);
            }
        __builtin_amdgcn_s_setprio(0);
        __builtin_amdgcn_s_barrier();   // safe for next iter's stage to overwrite cur
    }

    const int drow = (lane >> 4) * 4;
#pragma unroll
    for (int bn = 0; bn < 4; ++bn) {
        const int col = nBase + wn + bn * 16 + dcol;
#pragma unroll
        for (int am = 0; am < 2; ++am) {
#pragma unroll
            for (int r = 0; r < 4; ++r) {
                const int row = mBase + wm + am * 16 + drow + r;
                const float v = acc[am][bn][r] + bv[bn];
                if (mode == 0) {
                    outF[(size_t)row * N + col] = v;
                } else {
                    const int b = row >> 10, t = row & 1023;
                    const int h = col >> 6,  d = col & 63;
                    size_t idx;
                    if (mode == 1)
                        idx = (((size_t)(b * NHEADS + h)) * SEQ + t) * DHEAD + d;
                    else
                        idx = (((size_t)(b * NHEADS + h)) * DHEAD + d) * SEQ + t;
                    outHi[(size_t)z * MROWS * E_DIM + idx] = (bf16)v;
                }
            }
        }
    }
}

// ---------------------------------------------------------------------------
// MFMA flash attention (unchanged from round 6)
// ---------------------------------------------------------------------------
__global__ __launch_bounds__(512)
void attn_mfma_kernel(const bf16* __restrict__ qkv,
                      const bf16* __restrict__ mask_bf,     // pre-scaled by log2e
                      const unsigned char* __restrict__ kpad,
                      bf16* __restrict__ ctx_hi, bf16* __restrict__ ctx_lo)
{
    __shared__ bf16 Ks [2][4096];               // 16 KB
    __shared__ bf16 Vts[2][4096];               // 16 KB
    __shared__ bf16 Pn[8][1024];                // 16 KB, XOR-swizzled, wave-private

    const int tid  = threadIdx.x;
    const int lane = tid & 63;
    const int wid  = tid >> 6;          // 0..7
    const int c16  = lane & 15;
    const int quad = lane >> 4;

    const int bh = blockIdx.x;             // 0..127
    const int qt = blockIdx.y;             // 0..7
    const int b = bh >> 4, h = bh & 15;

    const size_t seg = (size_t)MROWS * E_DIM;
    const size_t headoff = (size_t)bh * SEQ * DHEAD;
    const bf16* Q_g  = qkv + headoff;
    const bf16* K_g  = qkv + seg + headoff;
    const bf16* Vt_g = qkv + 2 * seg + headoff;   // [d][t]

    const int qglob = qt * 128 + wid * 16 + c16;

    bf16x8 qf[2];
#pragma unroll
    for (int ks = 0; ks < 2; ++ks)
        qf[ks] = *(const bf16x8*)&Q_g[(size_t)qglob * DHEAD + quad * 8 + ks * 32];

    float l_i = 0.f;
    f32x4 oacc[4];
#pragma unroll
    for (int dt = 0; dt < 4; ++dt) oacc[dt] = (f32x4){0.f, 0.f, 0.f, 0.f};

    const int row0 = tid >> 3;                       // 0..63
    const int c0   = (tid & 7) ^ (row0 & 7);

    auto stage = [&](int kt, int bi) {
        const int ktb = kt * 64;
        const size_t k0 = (size_t)(ktb + row0) * DHEAD + c0 * 8;
        const size_t v0 = (size_t)row0 * SEQ + ktb + c0 * 8;
        __builtin_amdgcn_global_load_lds((gu32*)(K_g + k0),  (lu32*)&Ks [bi][wid * 512], 16, 0, 0);
        __builtin_amdgcn_global_load_lds((gu32*)(Vt_g + v0), (lu32*)&Vts[bi][wid * 512], 16, 0, 0);
    };

    stage(0, 0);
    __syncthreads();

    const int pxor = (c16 & 7) << 3;
    const size_t kpb = (size_t)b * SEQ + quad * 4;

#pragma unroll 1
    for (int kt = 0; kt < 16; ++kt) {
        const int cur = kt & 1;
        const int ktb = kt * 64;

        bf16x4 mvh[4];
        unsigned kpu[4];
#pragma unroll
        for (int st = 0; st < 4; ++st) {
            mvh[st] = *(const bf16x4*)&mask_bf[(size_t)qglob * SEQ + ktb + st * 16 + quad * 4];
            kpu[st] = *(const unsigned*)&kpad[kpb + ktb + st * 16];
        }

        if (kt < 15) stage(kt + 1, cur ^ 1);

        // ---- S^T = K.Q^T ----
        f32x4 sacc[4];
#pragma unroll
        for (int st = 0; st < 4; ++st) sacc[st] = (f32x4){0.f, 0.f, 0.f, 0.f};
        __builtin_amdgcn_s_setprio(1);
#pragma unroll
        for (int st = 0; st < 4; ++st) {
            const int row = st * 16 + c16;
            const int sw  = row & 7;
#pragma unroll
            for (int ks = 0; ks < 2; ++ks) {
                const int cp = ((quad + ks * 4) ^ sw);
                bf16x8 kh = *(const bf16x8*)&Ks[cur][(row * 8 + cp) * 8];
                sacc[st] = __builtin_amdgcn_mfma_f32_16x16x32_bf16(kh, qf[ks], sacc[st], 0, 0, 0);
            }
        }
        __builtin_amdgcn_s_setprio(0);

        // ---- softmax numerator (fixed exp2 base; no max tracking) ----
        float s[16];
#pragma unroll
        for (int st = 0; st < 4; ++st) {
#pragma unroll
            for (int r = 0; r < 4; ++r)
                s[st * 4 + r] = fmaf(sacc[st][r], 0.125f * LOG2E, (float)mvh[st][r]);
        }
        if (__any((kpu[0] | kpu[1] | kpu[2] | kpu[3]) != 0u)) {
#pragma unroll
            for (int st = 0; st < 4; ++st)
#pragma unroll
                for (int r = 0; r < 4; ++r)
                    if ((kpu[st] >> (r * 8)) & 0xff) s[st * 4 + r] = -2e30f;
        }
        float p[16];
#pragma unroll
        for (int i = 0; i < 16; ++i)
            p[i] = __builtin_amdgcn_exp2f(fminf(s[i], 30.f));   // overflow guard
        float u8[8];
#pragma unroll
        for (int i = 0; i < 8; ++i) u8[i] = p[i] + p[i + 8];
#pragma unroll
        for (int i = 0; i < 4; ++i) u8[i] += u8[i + 4];
        float ps = (u8[0] + u8[1]) + (u8[2] + u8[3]);
        ps += __shfl_xor(ps, 16, 64);
        ps += __shfl_xor(ps, 32, 64);
        l_i += ps;

        // ---- P (bf16) via XOR-swizzled wave-private LDS ----
#pragma unroll
        for (int st = 0; st < 4; ++st) {
            bf16x4 ph;
#pragma unroll
            for (int r = 0; r < 4; ++r) ph[r] = (bf16)p[st * 4 + r];
            *(bf16x4*)&Pn[wid][c16 * 64 + ((st * 16 + quad * 4) ^ pxor)] = ph;
        }
        bf16x8 pf[2];
#pragma unroll
        for (int ks = 0; ks < 2; ++ks)
            pf[ks] = *(const bf16x8*)&Pn[wid][c16 * 64 + ((ks * 32 + quad * 8) ^ pxor)];

        // ---- O^T += V^T.P ----
        __builtin_amdgcn_s_setprio(1);
#pragma unroll
        for (int dt = 0; dt < 4; ++dt) {
            const int row = dt * 16 + c16;
            const int sw  = row & 7;
#pragma unroll
            for (int ks = 0; ks < 2; ++ks) {
                const int cp = ((quad + ks * 4) ^ sw);
                bf16x8 vh = *(const bf16x8*)&Vts[cur][(row * 8 + cp) * 8];
                oacc[dt] = __builtin_amdgcn_mfma_f32_16x16x32_bf16(vh, pf[ks], oacc[dt], 0, 0, 0);
            }
        }
        __builtin_amdgcn_s_setprio(0);

        __syncthreads();   // drains prefetch(kt+1); guards buffer reuse
    }

    // ---- epilogue: split O into hi/lo for the out-projection ----
    const float invl = 1.0f / l_i;
#pragma unroll
    for (int dt = 0; dt < 4; ++dt) {
        bf16x4 oh, ol;
#pragma unroll
        for (int r = 0; r < 4; ++r) {
            float v = oacc[dt][r] * invl;
            oh[r] = (bf16)v;
            ol[r] = (bf16)(v - (float)oh[r]);
        }
        size_t idx = ((size_t)b * SEQ + qglob) * E_DIM + h * DHEAD + dt * 16 + quad * 4;
        *(bf16x4*)&ctx_hi[idx] = oh;
        *(bf16x4*)&ctx_lo[idx] = ol;
    }
}

// ---------------------------------------------------------------------------
extern "C" void kernel_launch(void* const* d_in, const int* in_sizes, int n_in,
                              void* d_out, int out_size, void* d_ws, size_t ws_size,
                              hipStream_t stream)
{
    const float* q_in = (const float*)d_in[0];
    const float* k_in = (const float*)d_in[1];
    const float* v_in = (const float*)d_in[2];
    const unsigned char* kpad = (const unsigned char*)d_in[3];
    const float* attn_mask = (const float*)d_in[4];
    const float* w_in  = (const float*)d_in[5];
    const float* b_in  = (const float*)d_in[6];
    const float* w_out = (const float*)d_in[7];
    const float* b_out = (const float*)d_in[8];
    float* out = (float*)d_out;

    char* ws = (char*)d_ws;
    const size_t MB = 1024 * 1024;
    bf16* w_in_hi  = (bf16*)(ws + 0 * MB);    // 6MB
    bf16* w_in_lo  = (bf16*)(ws + 6 * MB);    // 6MB
    bf16* w_out_hi = (bf16*)(ws + 12 * MB);   // 2MB
    bf16* w_out_lo = (bf16*)(ws + 14 * MB);   // 2MB
    bf16* qkv      = (bf16*)(ws + 16 * MB);   // 48MB (Q,K,Vt bf16)
    bf16* mask_bf  = (bf16*)(ws + 64 * MB);   // 2MB
    bf16* ctx_hi   = (bf16*)(ws + 66 * MB);   // 16MB
    bf16* ctx_lo   = (bf16*)(ws + 82 * MB);   // 16MB

    split_kernel<<<(3 * E_DIM * E_DIM / 4 + 255) / 256, 256, 0, stream>>>(
        w_in, w_in_hi, w_in_lo, 3 * E_DIM * E_DIM / 4);
    split_kernel<<<(E_DIM * E_DIM / 4 + 255) / 256, 256, 0, stream>>>(
        w_out, w_out_hi, w_out_lo, E_DIM * E_DIM / 4);
    cvt_bf16_kernel<<<(SEQ * SEQ / 4 + 255) / 256, 256, 0, stream>>>(
        attn_mask, mask_bf, LOG2E, SEQ * SEQ / 4);

    // fused in-projection: one dispatch, z = {q,k,v}
    gemm_nt_mfma<1><<<dim3(512, 3), 512, 0, stream>>>(
        q_in, k_in, v_in,
        nullptr, nullptr,
        w_in_hi, w_in_lo, b_in,
        nullptr, qkv,
        MROWS, E_DIM, E_DIM);

    attn_mfma_kernel<<<dim3(BATCH * NHEADS, SEQ / 128), 512, 0, stream>>>(
        qkv, mask_bf, kpad, ctx_hi, ctx_lo);

    gemm_nt_mfma<0><<<dim3(512, 1), 512, 0, stream>>>(
        nullptr, nullptr, nullptr,
        ctx_hi, ctx_lo, w_out_hi, w_out_lo, b_out,
        out, nullptr,
        MROWS, E_DIM, E_DIM);
}